// Round 9
// baseline (301.167 us; speedup 1.0000x reference)
//
#include <hip/hip_runtime.h>
#include <hip/hip_bf16.h>

#define NN 50000
#define EE 1600000
#define PROJ_BLOCKS 1563     // ceil(NN/32) 32-row MFMA tiles
#define SLOTS 32             // direct slab slots per dst (deg ~ Poisson(32))
#define OVF_CAP 262144       // deterministic total overflow ~113K; 2.3x margin

using short8 = __attribute__((ext_vector_type(8))) short;   // 8 bf16 (4 VGPRs)
using float4v = __attribute__((ext_vector_type(4))) float;  // MFMA accumulator

__device__ __forceinline__ float bflo(unsigned u) { return __uint_as_float(u << 16); }
__device__ __forceinline__ float bfhi(unsigned u) { return __uint_as_float(u & 0xffff0000u); }
__device__ __forceinline__ unsigned short f2bf(float v) {
  return __bfloat16_as_ushort(__float2bfloat16(v));
}

// ---------------- K0: a_src/a_dst via collapsed matvec + slab init + W^T bf16 -------
// Wave-loop VERBATIM R7 (passing). Init: cnt=0 / head1=-1 / ovf cursor=0, grid-stride
// in k_pre (the pattern every passing round used).
__global__ __launch_bounds__(256) void k_pre(
    const float* __restrict__ x, const float* __restrict__ W,
    const float* __restrict__ att_src, const float* __restrict__ att_dst,
    float2* __restrict__ a_src2, float2* __restrict__ a_dst2,
    int* __restrict__ cnt, int* __restrict__ head1, int* __restrict__ ovf_cur,
    unsigned short* __restrict__ wt16, int nblocks) {
  __shared__ float wa_s[128][2], wa_d[128][2];
  int tid = threadIdx.x;
  {
    int k = tid >> 1, hh = tid & 1;
    const float* wrow = W + k * 64 + hh * 32;
    const float* as = att_src + hh * 32;
    const float* ad = att_dst + hh * 32;
    float ss = 0.f, dd = 0.f;
#pragma unroll 8
    for (int c = 0; c < 32; ++c) { float wv = wrow[c]; ss += wv * as[c]; dd += wv * ad[c]; }
    wa_s[k][hh] = ss; wa_d[k][hh] = dd;
  }
  if (blockIdx.x < 32) {
    int i = blockIdx.x * 256 + tid;
    int k = i >> 6, n = i & 63;
    wt16[n * 128 + k] = f2bf(W[i]);
  }
  if (blockIdx.x == 0 && tid == 0) *ovf_cur = 0;
  int gsize = nblocks * 256;
  for (int i = blockIdx.x * 256 + tid; i < NN; i += gsize) { cnt[i] = 0; head1[i] = -1; }
  __syncthreads();

  int w = tid >> 6, lane = tid & 63;
  int g = lane >> 4, q = lane & 15;      // 4 node-groups of 16 lanes per wave
  int k0 = q * 8;
  float ws0[8], ws1[8], wd0[8], wd1[8];
#pragma unroll
  for (int j = 0; j < 8; ++j) {
    ws0[j] = wa_s[k0 + j][0]; ws1[j] = wa_s[k0 + j][1];
    wd0[j] = wa_d[k0 + j][0]; wd1[j] = wa_d[k0 + j][1];
  }
  int stride = nblocks * 16;             // nodes per grid sweep (4 waves x 4 groups)
  for (int n = blockIdx.x * 16 + w * 4 + g; n < NN; n += stride) {
    float4 xa = *(const float4*)&x[n * 128 + k0];
    float4 xb = *(const float4*)&x[n * 128 + k0 + 4];
    float v[8] = {xa.x, xa.y, xa.z, xa.w, xb.x, xb.y, xb.z, xb.w};
    float s0 = 0.f, s1 = 0.f, d0 = 0.f, d1 = 0.f;
#pragma unroll
    for (int j = 0; j < 8; ++j) {
      float e = v[j] > 0.f ? v[j] : __expf(v[j]) - 1.f;
      s0 += e * ws0[j]; s1 += e * ws1[j];
      d0 += e * wd0[j]; d1 += e * wd1[j];
    }
#pragma unroll
    for (int o = 8; o > 0; o >>= 1) {    // reduce within the 16-lane group
      s0 += __shfl_xor(s0, o); s1 += __shfl_xor(s1, o);
      d0 += __shfl_xor(d0, o); d1 += __shfl_xor(d1, o);
    }
    if (q == 0) { a_src2[n] = make_float2(s0, s1); a_dst2[n] = make_float2(d0, d1); }
  }
}

// ---------------- K1: FUSED proj + build --------------
// proj part VERBATIM R7. build part: same weight math as R7, but the record
// {src, w0|w1 bf16-packed} (8 B) goes to the dst-clustered slab slot from
// atomicAdd(&cnt[dst]). Overflow (pos>=32, ~7% of edges, deterministic total ~113K)
// chains off head1[dst] via a SINGLE wave-aggregated global cursor.
__global__ __launch_bounds__(256) void k_mid(
    const float* __restrict__ x, const unsigned short* __restrict__ wt16,
    const int* __restrict__ src, const int* __restrict__ dst,
    const float2* __restrict__ a_src2, const float2* __restrict__ a_dst2,
    int* __restrict__ cnt, int* __restrict__ head1, int* __restrict__ ovf_cur,
    int2* __restrict__ slab, int4* __restrict__ ovf, unsigned* __restrict__ h2u) {
  int bid = blockIdx.x;
  int tid = threadIdx.x;
  if (bid >= PROJ_BLOCKS) {
    int ea = (bid - PROJ_BLOCKS) * 512 + tid;
    int eb = ea + 256;
    int sa = src[ea], da = dst[ea];
    int sbn = src[eb], db = dst[eb];
    float2 asa = a_src2[sa], ada = a_dst2[da];
    float2 asb = a_src2[sbn], adb = a_dst2[db];
    float la0 = asa.x + ada.x; la0 = fmaxf(la0, 0.2f * la0);
    float la1 = asa.y + ada.y; la1 = fmaxf(la1, 0.2f * la1);
    float lb0 = asb.x + adb.x; lb0 = fmaxf(lb0, 0.2f * lb0);
    float lb1 = asb.y + adb.y; lb1 = fmaxf(lb1, 0.2f * lb1);
    unsigned wa = (unsigned)f2bf(__expf(la0)) | ((unsigned)f2bf(__expf(la1)) << 16);
    unsigned wb = (unsigned)f2bf(__expf(lb0)) | ((unsigned)f2bf(__expf(lb1)) << 16);
    int pa = atomicAdd(&cnt[da], 1);
    if (pa < SLOTS) {
      slab[da * SLOTS + pa] = make_int2(sa, (int)wa);
    } else {
      int op = atomicAdd(ovf_cur, 1);               // wave-aggregated same-address add
      int old = atomicExch(&head1[da], op);
      ovf[op] = make_int4(sa, old, (int)wa, 0);
    }
    int pb = atomicAdd(&cnt[db], 1);
    if (pb < SLOTS) {
      slab[db * SLOTS + pb] = make_int2(sbn, (int)wb);
    } else {
      int op = atomicAdd(ovf_cur, 1);
      int old = atomicExch(&head1[db], op);
      ovf[op] = make_int4(sbn, old, (int)wb, 0);
    }
    return;
  }
  __shared__ unsigned short Wt[64 * 136];   // [n][k] bf16 (W^T), padded, 17.4 KB
  __shared__ unsigned short xs[32 * 136];   // [r][k] bf16 (ELU applied), 8.7 KB
  int row0 = bid * 32;
#pragma unroll
  for (int it = 0; it < 4; ++it) {          // stage W^T: 16B vector copy from wt16
    int idx = it * 2048 + tid * 8;          // idx = n*128 + k, k 8-aligned
    int n = idx >> 7, k = idx & 127;
    *(short8*)&Wt[n * 136 + k] = *(const short8*)&wt16[idx];
  }
  for (int i = tid; i < 2048; i += 256) {          // stage x rows (ELU, bf16, packed)
    int r = i >> 6, k2 = (i & 63) * 2;
    int row = row0 + r;
    float v0 = 0.f, v1 = 0.f;
    if (row < NN) { float2 xv = *(const float2*)&x[row * 128 + k2]; v0 = xv.x; v1 = xv.y; }
    v0 = v0 > 0.f ? v0 : __expf(v0) - 1.f;
    v1 = v1 > 0.f ? v1 : __expf(v1) - 1.f;
    *(unsigned*)&xs[r * 136 + k2] = (unsigned)f2bf(v0) | ((unsigned)f2bf(v1) << 16);
  }
  __syncthreads();
  int w = tid >> 6, lane = tid & 63;
  int t = w >> 1, ch = w & 1;               // row-tile, column-half
  int m = lane & 15, quad = lane >> 4;
  float4v acc[2] = {{0, 0, 0, 0}, {0, 0, 0, 0}};
#pragma unroll
  for (int ks = 0; ks < 4; ++ks) {
    int koff = quad * 8 + ks * 32;
    short8 af = *(const short8*)&xs[(t * 16 + m) * 136 + koff];
#pragma unroll
    for (int j = 0; j < 2; ++j) {
      int nt = ch * 2 + j;
      short8 bf = *(const short8*)&Wt[(nt * 16 + m) * 136 + koff];
      acc[j] = __builtin_amdgcn_mfma_f32_16x16x32_bf16(af, bf, acc[j], 0, 0, 0);
    }
  }
#pragma unroll
  for (int j = 0; j < 2; ++j) {
    int nt = ch * 2 + j;
#pragma unroll
    for (int reg = 0; reg < 4; ++reg) {
      float v = acc[j][reg];
      float vhi = __shfl_xor(v, 1);          // partner column (m^1)
      int row = row0 + t * 16 + quad * 4 + reg;
      if (!(m & 1) && row < NN) {
        h2u[row * 32 + nt * 8 + (m >> 1)] =
            (unsigned)f2bf(v) | ((unsigned)f2bf(vhi) << 16);
      }
    }
  }
}

// ---------------- K2: weighted aggregate — slab walk ----------
// Node per half-wave (R5). Records for node n are CONTIGUOUS at slab[n*32..]:
// 8 B each, so 32 records = 4 fully-consumed 64 B lines with computable addresses
// (no pointer chase). Tail slots are clamped to record 0's id with weight 0 (ids
// from unwritten slots are never dereferenced). Then the short overflow chain.
__global__ __launch_bounds__(256) void k_agg(
    const unsigned* __restrict__ h2u, const float2* __restrict__ a_src2,
    const float2* __restrict__ a_dst2, const int* __restrict__ cnt,
    const int* __restrict__ head1, const int2* __restrict__ slab,
    const int4* __restrict__ ovf, const float* __restrict__ bias,
    float* __restrict__ out) {
  int lane = threadIdx.x & 63;
  int half = lane >> 5;
  int n = blockIdx.x * 8 + (threadIdx.x >> 6) * 2 + half;   // node per half-wave
  int c2 = lane & 31;          // column pair: cols 2*c2, 2*c2+1
  int hh = c2 >> 4;            // head of this lane's columns

  float denom, acc0, acc1;
  {   // self loop (PyG add_self_loops), counted once; weight in full f32
    float2 as = a_src2[n], ad = a_dst2[n];
    float l0 = (hh ? as.y + ad.y : as.x + ad.x);
    l0 = fmaxf(l0, 0.2f * l0);
    float es = __expf(l0);
    unsigned hv = h2u[n * 32 + c2];
    denom = es; acc0 = es * bflo(hv); acc1 = es * bfhi(hv);
  }

  int cv = cnt[n];
  int m32 = cv < SLOTS ? cv : SLOTS;
  const int4* sb4 = (const int4*)(slab + (long)n * SLOTS);   // 2 records per int4
  for (int j = 0; j < m32; j += 4) {       // half-uniform trip count
    int4 ra = sb4[j >> 1];                 // records j, j+1
    int4 rb = sb4[(j >> 1) + 1];           // records j+2, j+3 (within 32-slot row)
    bool v1 = (j + 1 < m32), v2 = (j + 2 < m32), v3 = (j + 3 < m32);
    int i0 = ra.x;
    int i1 = v1 ? ra.z : i0;
    int i2 = v2 ? rb.x : i0;
    int i3 = v3 ? rb.z : i0;
    unsigned h0 = h2u[i0 * 32 + c2], h1 = h2u[i1 * 32 + c2];
    unsigned h2 = h2u[i2 * 32 + c2], h3 = h2u[i3 * 32 + c2];
    unsigned w0p = (unsigned)ra.y, w1p = (unsigned)ra.w;
    unsigned w2p = (unsigned)rb.y, w3p = (unsigned)rb.w;
    float x0 = hh ? bfhi(w0p) : bflo(w0p);               // j < m32 always
    float x1 = v1 ? (hh ? bfhi(w1p) : bflo(w1p)) : 0.f;
    float x2 = v2 ? (hh ? bfhi(w2p) : bflo(w2p)) : 0.f;
    float x3 = v3 ? (hh ? bfhi(w3p) : bflo(w3p)) : 0.f;
    denom += (x0 + x1) + (x2 + x3);
    acc0 += x0 * bflo(h0) + x1 * bflo(h1) + x2 * bflo(h2) + x3 * bflo(h3);
    acc1 += x0 * bfhi(h0) + x1 * bfhi(h1) + x2 * bfhi(h2) + x3 * bfhi(h3);
  }
  int e = head1[n];                         // overflow chain (half-uniform)
  while (e >= 0) {
    int4 p = ovf[e];
    unsigned hv = h2u[p.x * 32 + c2];
    unsigned wp = (unsigned)p.z;
    float xw = hh ? bfhi(wp) : bflo(wp);
    denom += xw;
    acc0 += xw * bflo(hv);
    acc1 += xw * bfhi(hv);
    e = p.y;
  }

  float inv = 1.f / (denom + 1e-16f);
  float2 b = ((const float2*)bias)[c2];
  ((float2*)out)[n * 32 + c2] = make_float2(acc0 * inv + b.x, acc1 * inv + b.y);
}

extern "C" void kernel_launch(void* const* d_in, const int* in_sizes, int n_in,
                              void* d_out, int out_size, void* d_ws, size_t ws_size,
                              hipStream_t stream) {
  const float* x       = (const float*)d_in[0];
  const float* W       = (const float*)d_in[1];
  const float* att_src = (const float*)d_in[2];
  const float* att_dst = (const float*)d_in[3];
  const float* bias    = (const float*)d_in[4];
  const int* edge_index = (const int*)d_in[5];
  const int* esrc = edge_index;        // edge_index[0, :]
  const int* edst = edge_index + EE;   // edge_index[1, :]

  // Workspace layout (peak 24.68 MB -- well inside the 34.4 MB proven envelope):
  char* base = (char*)d_ws;
  unsigned* h2u   = (unsigned*)base;                     // [0      .. 6.4M)  h bf16x2
  float2* a_src2  = (float2*)(base + 6400000);           // [6.4M   .. 6.8M)
  float2* a_dst2  = (float2*)(base + 6800000);           // [6.8M   .. 7.2M)
  int*    cnt     = (int*)(base + 7200000);              // [7.2M   .. 7.4M)  50K i32
  int*    head1   = (int*)(base + 7400000);              // [7.4M   .. 7.6M)  50K i32
  int*    ovf_cur = (int*)(base + 7600000);              // [7.6M   .. +4B)   1 i32
  int2*   slab    = (int2*)(base + 7680000);             // [7.68M  .. 20.48M) 50K*32*8B
  int4*   ovf     = (int4*)(base + 20480000);            // [20.48M .. 24.68M) 262K*16B
  // bf16 W^T scratch lives in the OUTPUT buffer (12.8 MB, only written by k_agg,
  // stream-ordered after k_mid's reads) -- avoids growing the workspace.
  unsigned short* wt16 = (unsigned short*)d_out;         // [0 .. 16K) of d_out

  const int PRE_BLOCKS = 1024;
  k_pre<<<PRE_BLOCKS, 256, 0, stream>>>(x, W, att_src, att_dst, a_src2, a_dst2,
                                        cnt, head1, ovf_cur, wt16, PRE_BLOCKS);
  k_mid<<<PROJ_BLOCKS + EE / 512, 256, 0, stream>>>(x, wt16, esrc, edst, a_src2,
                                                    a_dst2, cnt, head1, ovf_cur,
                                                    slab, ovf, h2u);
  k_agg<<<NN / 8, 256, 0, stream>>>(h2u, a_src2, a_dst2, cnt, head1, slab, ovf,
                                    bias, (float*)d_out);
}

// Round 11
// 234.029 us; speedup vs baseline: 1.2869x; 1.2869x over previous
//
#include <hip/hip_runtime.h>
#include <hip/hip_bf16.h>

#define NN 50000
#define EE 1600000
#define PROJ_BLOCKS 1563     // ceil(NN/32) 32-row MFMA tiles
#define SRC_SPLIT 25000      // src-half boundary for phased chains

using short8 = __attribute__((ext_vector_type(8))) short;   // 8 bf16 (4 VGPRs)
using float4v = __attribute__((ext_vector_type(4))) float;  // MFMA accumulator
using int4v  = __attribute__((ext_vector_type(4))) int;     // nt-store-compatible 16B

__device__ __forceinline__ float bflo(unsigned u) { return __uint_as_float(u << 16); }
__device__ __forceinline__ float bfhi(unsigned u) { return __uint_as_float(u & 0xffff0000u); }
__device__ __forceinline__ unsigned short f2bf(float v) {
  return __bfloat16_as_ushort(__float2bfloat16(v));
}

// ---------------- K0: a_src/a_dst via collapsed matvec + head8 init + W^T bf16 -------
// VERBATIM R7 (passing, 228.9 us config).
__global__ __launch_bounds__(256) void k_pre(
    const float* __restrict__ x, const float* __restrict__ W,
    const float* __restrict__ att_src, const float* __restrict__ att_dst,
    float2* __restrict__ a_src2, float2* __restrict__ a_dst2,
    int* __restrict__ head8, unsigned short* __restrict__ wt16, int nblocks) {
  __shared__ float wa_s[128][2], wa_d[128][2];
  int tid = threadIdx.x;
  {
    int k = tid >> 1, hh = tid & 1;
    const float* wrow = W + k * 64 + hh * 32;
    const float* as = att_src + hh * 32;
    const float* ad = att_dst + hh * 32;
    float ss = 0.f, dd = 0.f;
#pragma unroll 8
    for (int c = 0; c < 32; ++c) { float wv = wrow[c]; ss += wv * as[c]; dd += wv * ad[c]; }
    wa_s[k][hh] = ss; wa_d[k][hh] = dd;
  }
  if (blockIdx.x < 32) {
    int i = blockIdx.x * 256 + tid;
    int k = i >> 6, n = i & 63;
    wt16[n * 128 + k] = f2bf(W[i]);
  }
  int gsize = nblocks * 256;
  for (int i = blockIdx.x * 256 + tid; i < NN * 8; i += gsize) head8[i] = -1;
  __syncthreads();

  int w = tid >> 6, lane = tid & 63;
  int g = lane >> 4, q = lane & 15;      // 4 node-groups of 16 lanes per wave
  int k0 = q * 8;
  float ws0[8], ws1[8], wd0[8], wd1[8];
#pragma unroll
  for (int j = 0; j < 8; ++j) {
    ws0[j] = wa_s[k0 + j][0]; ws1[j] = wa_s[k0 + j][1];
    wd0[j] = wa_d[k0 + j][0]; wd1[j] = wa_d[k0 + j][1];
  }
  int stride = nblocks * 16;             // nodes per grid sweep (4 waves x 4 groups)
  for (int n = blockIdx.x * 16 + w * 4 + g; n < NN; n += stride) {
    float4 xa = *(const float4*)&x[n * 128 + k0];
    float4 xb = *(const float4*)&x[n * 128 + k0 + 4];
    float v[8] = {xa.x, xa.y, xa.z, xa.w, xb.x, xb.y, xb.z, xb.w};
    float s0 = 0.f, s1 = 0.f, d0 = 0.f, d1 = 0.f;
#pragma unroll
    for (int j = 0; j < 8; ++j) {
      float e = v[j] > 0.f ? v[j] : __expf(v[j]) - 1.f;
      s0 += e * ws0[j]; s1 += e * ws1[j];
      d0 += e * wd0[j]; d1 += e * wd1[j];
    }
#pragma unroll
    for (int o = 8; o > 0; o >>= 1) {    // reduce within the 16-lane group
      s0 += __shfl_xor(s0, o); s1 += __shfl_xor(s1, o);
      d0 += __shfl_xor(d0, o); d1 += __shfl_xor(d1, o);
    }
    if (q == 0) { a_src2[n] = make_float2(s0, s1); a_dst2[n] = make_float2(d0, d1); }
  }
}

// ---------------- K1: FUSED proj + build (R7 body) --------------
// ONLY change vs R7: edge4 records are written with non-temporal stores (via
// ext_vector int4v -- HIP's int4 struct is rejected by the builtin). edge4 is a
// 25.6 MB one-touch stream; keeping it out of L2 preserves residency for the 1.6 MB
// head8 atomic working set (pure cache hint -- no data-flow change).
__global__ __launch_bounds__(256) void k_mid(
    const float* __restrict__ x, const unsigned short* __restrict__ wt16,
    const int* __restrict__ src, const int* __restrict__ dst,
    const float2* __restrict__ a_src2, const float2* __restrict__ a_dst2,
    int* __restrict__ head8, int4* __restrict__ edge4, unsigned* __restrict__ h2u) {
  int bid = blockIdx.x;
  int tid = threadIdx.x;
  if (bid >= PROJ_BLOCKS) {
    int ea = (bid - PROJ_BLOCKS) * 512 + tid;
    int eb = ea + 256;
    int sa = src[ea], da = dst[ea];
    int sb = src[eb], db = dst[eb];
    float2 asa = a_src2[sa], ada = a_dst2[da];
    float2 asb = a_src2[sb], adb = a_dst2[db];
    float la0 = asa.x + ada.x; la0 = fmaxf(la0, 0.2f * la0);
    float la1 = asa.y + ada.y; la1 = fmaxf(la1, 0.2f * la1);
    float lb0 = asb.x + adb.x; lb0 = fmaxf(lb0, 0.2f * lb0);
    float lb1 = asb.y + adb.y; lb1 = fmaxf(lb1, 0.2f * lb1);
    int ca = ((sa >= SRC_SPLIT) ? 4 : 0) + (ea & 3);   // src-half keyed chain
    int cb = ((sb >= SRC_SPLIT) ? 4 : 0) + (eb & 3);
    int olda = atomicExch(&head8[da * 8 + ca], ea);
    int oldb = atomicExch(&head8[db * 8 + cb], eb);
    int4v ra = {sa, olda, __float_as_int(__expf(la0)), __float_as_int(__expf(la1))};
    int4v rb = {sb, oldb, __float_as_int(__expf(lb0)), __float_as_int(__expf(lb1))};
    __builtin_nontemporal_store(ra, (int4v*)&edge4[ea]);
    __builtin_nontemporal_store(rb, (int4v*)&edge4[eb]);
    return;
  }
  __shared__ unsigned short Wt[64 * 136];   // [n][k] bf16 (W^T), padded, 17.4 KB
  __shared__ unsigned short xs[32 * 136];   // [r][k] bf16 (ELU applied), 8.7 KB
  int row0 = bid * 32;
#pragma unroll
  for (int it = 0; it < 4; ++it) {          // stage W^T: 16B vector copy from wt16
    int idx = it * 2048 + tid * 8;          // idx = n*128 + k, k 8-aligned
    int n = idx >> 7, k = idx & 127;
    *(short8*)&Wt[n * 136 + k] = *(const short8*)&wt16[idx];
  }
  for (int i = tid; i < 2048; i += 256) {          // stage x rows (ELU, bf16, packed)
    int r = i >> 6, k2 = (i & 63) * 2;
    int row = row0 + r;
    float v0 = 0.f, v1 = 0.f;
    if (row < NN) { float2 xv = *(const float2*)&x[row * 128 + k2]; v0 = xv.x; v1 = xv.y; }
    v0 = v0 > 0.f ? v0 : __expf(v0) - 1.f;
    v1 = v1 > 0.f ? v1 : __expf(v1) - 1.f;
    *(unsigned*)&xs[r * 136 + k2] = (unsigned)f2bf(v0) | ((unsigned)f2bf(v1) << 16);
  }
  __syncthreads();
  int w = tid >> 6, lane = tid & 63;
  int t = w >> 1, ch = w & 1;               // row-tile, column-half
  int m = lane & 15, quad = lane >> 4;
  float4v acc[2] = {{0, 0, 0, 0}, {0, 0, 0, 0}};
#pragma unroll
  for (int ks = 0; ks < 4; ++ks) {
    int koff = quad * 8 + ks * 32;
    short8 af = *(const short8*)&xs[(t * 16 + m) * 136 + koff];
#pragma unroll
    for (int j = 0; j < 2; ++j) {
      int nt = ch * 2 + j;
      short8 bf = *(const short8*)&Wt[(nt * 16 + m) * 136 + koff];
      acc[j] = __builtin_amdgcn_mfma_f32_16x16x32_bf16(af, bf, acc[j], 0, 0, 0);
    }
  }
#pragma unroll
  for (int j = 0; j < 2; ++j) {
    int nt = ch * 2 + j;
#pragma unroll
    for (int reg = 0; reg < 4; ++reg) {
      float v = acc[j][reg];
      float vhi = __shfl_xor(v, 1);          // partner column (m^1)
      int row = row0 + t * 16 + quad * 4 + reg;
      if (!(m & 1) && row < NN) {
        h2u[row * 32 + nt * 8 + (m >> 1)] =
            (unsigned)f2bf(v) | ((unsigned)f2bf(vhi) << 16);
      }
    }
  }
}

// ---------------- K2: weighted aggregate — src-phased chain walk (VERBATIM R7) -------
__global__ __launch_bounds__(256) void k_agg(
    const unsigned* __restrict__ h2u, const float2* __restrict__ a_src2,
    const float2* __restrict__ a_dst2, const int4* __restrict__ head8v,
    const int4* __restrict__ edge4, const float* __restrict__ bias,
    float* __restrict__ out) {
  int lane = threadIdx.x & 63;
  int half = lane >> 5;
  int n = blockIdx.x * 8 + (threadIdx.x >> 6) * 2 + half;   // node per half-wave
  int c2 = lane & 31;          // column pair: cols 2*c2, 2*c2+1
  int hh = c2 >> 4;            // head of this lane's columns

  float denom, acc0, acc1;
  {   // self loop (PyG add_self_loops), counted once
    float2 as = a_src2[n], ad = a_dst2[n];
    float l0 = (hh ? as.y + ad.y : as.x + ad.x);
    l0 = fmaxf(l0, 0.2f * l0);
    float es = __expf(l0);
    unsigned hv = h2u[n * 32 + c2];
    denom = es; acc0 = es * bflo(hv); acc1 = es * bfhi(hv);
  }

  int4 hdA = head8v[n * 2];        // chains 0..3: src < SRC_SPLIT
  int4 hdB = head8v[n * 2 + 1];    // chains 4..7: src >= SRC_SPLIT
#pragma unroll
  for (int ph = 0; ph < 2; ++ph) {
    int4 hd = ph ? hdB : hdA;
    int e0 = hd.x, e1 = hd.y, e2 = hd.z, e3 = hd.w;
    while (max(max(e0, e1), max(e2, e3)) >= 0) {   // half-uniform
      int4 p0 = edge4[max(e0, 0)];
      int4 p1 = edge4[max(e1, 0)];
      int4 p2 = edge4[max(e2, 0)];
      int4 p3 = edge4[max(e3, 0)];
      unsigned h0 = h2u[p0.x * 32 + c2], h1 = h2u[p1.x * 32 + c2];
      unsigned h2 = h2u[p2.x * 32 + c2], h3 = h2u[p3.x * 32 + c2];
      float x0 = (e0 >= 0) ? __int_as_float(hh ? p0.w : p0.z) : 0.f;
      float x1 = (e1 >= 0) ? __int_as_float(hh ? p1.w : p1.z) : 0.f;
      float x2 = (e2 >= 0) ? __int_as_float(hh ? p2.w : p2.z) : 0.f;
      float x3 = (e3 >= 0) ? __int_as_float(hh ? p3.w : p3.z) : 0.f;
      denom += (x0 + x1) + (x2 + x3);
      acc0 += x0 * bflo(h0) + x1 * bflo(h1) + x2 * bflo(h2) + x3 * bflo(h3);
      acc1 += x0 * bfhi(h0) + x1 * bfhi(h1) + x2 * bfhi(h2) + x3 * bfhi(h3);
      e0 = (e0 >= 0) ? p0.y : -1;
      e1 = (e1 >= 0) ? p1.y : -1;
      e2 = (e2 >= 0) ? p2.y : -1;
      e3 = (e3 >= 0) ? p3.y : -1;
    }
  }
  float inv = 1.f / (denom + 1e-16f);
  float2 b = ((const float2*)bias)[c2];
  ((float2*)out)[n * 32 + c2] = make_float2(acc0 * inv + b.x, acc1 * inv + b.y);
}

extern "C" void kernel_launch(void* const* d_in, const int* in_sizes, int n_in,
                              void* d_out, int out_size, void* d_ws, size_t ws_size,
                              hipStream_t stream) {
  const float* x       = (const float*)d_in[0];
  const float* W       = (const float*)d_in[1];
  const float* att_src = (const float*)d_in[2];
  const float* att_dst = (const float*)d_in[3];
  const float* bias    = (const float*)d_in[4];
  const int* edge_index = (const int*)d_in[5];
  const int* esrc = edge_index;        // edge_index[0, :]
  const int* edst = edge_index + EE;   // edge_index[1, :]

  // Workspace layout:
  char* base = (char*)d_ws;
  unsigned* h2u  = (unsigned*)base;                      // [0     .. 6.4M)   h bf16x2
  float2* a_src2 = (float2*)(base + 6400000);            // [6.4M  .. 6.8M)  50K float2
  float2* a_dst2 = (float2*)(base + 6800000);            // [6.8M  .. 7.2M)  50K float2
  int*    head8  = (int*)(base + 7200000);               // [7.2M  .. 8.8M)  400K i32
  int4*   edge4  = (int4*)(base + 8800000);              // [8.8M  .. 34.4M) 1.6M int4
  // bf16 W^T scratch lives in the OUTPUT buffer (12.8 MB, only written by k_agg,
  // stream-ordered after k_mid's reads) -- avoids growing the workspace.
  unsigned short* wt16 = (unsigned short*)d_out;         // [0 .. 16K) of d_out

  const int PRE_BLOCKS = 1024;
  k_pre<<<PRE_BLOCKS, 256, 0, stream>>>(x, W, att_src, att_dst, a_src2, a_dst2,
                                        head8, wt16, PRE_BLOCKS);
  k_mid<<<PROJ_BLOCKS + EE / 512, 256, 0, stream>>>(x, wt16, esrc, edst, a_src2,
                                                    a_dst2, head8, edge4, h2u);
  k_agg<<<NN / 8, 256, 0, stream>>>(h2u, a_src2, a_dst2, (const int4*)head8,
                                    edge4, bias, (float*)d_out);
}

// Round 12
// 226.751 us; speedup vs baseline: 1.3282x; 1.0321x over previous
//
#include <hip/hip_runtime.h>
#include <hip/hip_bf16.h>

#define NN 50000
#define EE 1600000
#define PROJ_BLOCKS 1563     // ceil(NN/32) 32-row MFMA tiles
#define SRC_SPLIT 25000      // src-half boundary for phased chains

using short8 = __attribute__((ext_vector_type(8))) short;   // 8 bf16 (4 VGPRs)
using float4v = __attribute__((ext_vector_type(4))) float;  // MFMA accumulator

__device__ __forceinline__ float bflo(unsigned u) { return __uint_as_float(u << 16); }
__device__ __forceinline__ float bfhi(unsigned u) { return __uint_as_float(u & 0xffff0000u); }
__device__ __forceinline__ unsigned short f2bf(float v) {
  return __bfloat16_as_ushort(__float2bfloat16(v));
}

// ---------------- K0: a_src/a_dst via collapsed matvec + head8 init + W^T bf16 -------
// VERBATIM R7 (best passing config, 228.9 us).
__global__ __launch_bounds__(256) void k_pre(
    const float* __restrict__ x, const float* __restrict__ W,
    const float* __restrict__ att_src, const float* __restrict__ att_dst,
    float2* __restrict__ a_src2, float2* __restrict__ a_dst2,
    int* __restrict__ head8, unsigned short* __restrict__ wt16, int nblocks) {
  __shared__ float wa_s[128][2], wa_d[128][2];
  int tid = threadIdx.x;
  {
    int k = tid >> 1, hh = tid & 1;
    const float* wrow = W + k * 64 + hh * 32;
    const float* as = att_src + hh * 32;
    const float* ad = att_dst + hh * 32;
    float ss = 0.f, dd = 0.f;
#pragma unroll 8
    for (int c = 0; c < 32; ++c) { float wv = wrow[c]; ss += wv * as[c]; dd += wv * ad[c]; }
    wa_s[k][hh] = ss; wa_d[k][hh] = dd;
  }
  if (blockIdx.x < 32) {
    int i = blockIdx.x * 256 + tid;
    int k = i >> 6, n = i & 63;
    wt16[n * 128 + k] = f2bf(W[i]);
  }
  int gsize = nblocks * 256;
  for (int i = blockIdx.x * 256 + tid; i < NN * 8; i += gsize) head8[i] = -1;
  __syncthreads();

  int w = tid >> 6, lane = tid & 63;
  int g = lane >> 4, q = lane & 15;      // 4 node-groups of 16 lanes per wave
  int k0 = q * 8;
  float ws0[8], ws1[8], wd0[8], wd1[8];
#pragma unroll
  for (int j = 0; j < 8; ++j) {
    ws0[j] = wa_s[k0 + j][0]; ws1[j] = wa_s[k0 + j][1];
    wd0[j] = wa_d[k0 + j][0]; wd1[j] = wa_d[k0 + j][1];
  }
  int stride = nblocks * 16;             // nodes per grid sweep (4 waves x 4 groups)
  for (int n = blockIdx.x * 16 + w * 4 + g; n < NN; n += stride) {
    float4 xa = *(const float4*)&x[n * 128 + k0];
    float4 xb = *(const float4*)&x[n * 128 + k0 + 4];
    float v[8] = {xa.x, xa.y, xa.z, xa.w, xb.x, xb.y, xb.z, xb.w};
    float s0 = 0.f, s1 = 0.f, d0 = 0.f, d1 = 0.f;
#pragma unroll
    for (int j = 0; j < 8; ++j) {
      float e = v[j] > 0.f ? v[j] : __expf(v[j]) - 1.f;
      s0 += e * ws0[j]; s1 += e * ws1[j];
      d0 += e * wd0[j]; d1 += e * wd1[j];
    }
#pragma unroll
    for (int o = 8; o > 0; o >>= 1) {    // reduce within the 16-lane group
      s0 += __shfl_xor(s0, o); s1 += __shfl_xor(s1, o);
      d0 += __shfl_xor(d0, o); d1 += __shfl_xor(d1, o);
    }
    if (q == 0) { a_src2[n] = make_float2(s0, s1); a_dst2[n] = make_float2(d0, d1); }
  }
}

// ---------------- K1: FUSED proj + build (VERBATIM R7; plain edge4 stores) ----------
__global__ __launch_bounds__(256) void k_mid(
    const float* __restrict__ x, const unsigned short* __restrict__ wt16,
    const int* __restrict__ src, const int* __restrict__ dst,
    const float2* __restrict__ a_src2, const float2* __restrict__ a_dst2,
    int* __restrict__ head8, int4* __restrict__ edge4, unsigned* __restrict__ h2u) {
  int bid = blockIdx.x;
  int tid = threadIdx.x;
  if (bid >= PROJ_BLOCKS) {
    int ea = (bid - PROJ_BLOCKS) * 512 + tid;
    int eb = ea + 256;
    int sa = src[ea], da = dst[ea];
    int sb = src[eb], db = dst[eb];
    float2 asa = a_src2[sa], ada = a_dst2[da];
    float2 asb = a_src2[sb], adb = a_dst2[db];
    float la0 = asa.x + ada.x; la0 = fmaxf(la0, 0.2f * la0);
    float la1 = asa.y + ada.y; la1 = fmaxf(la1, 0.2f * la1);
    float lb0 = asb.x + adb.x; lb0 = fmaxf(lb0, 0.2f * lb0);
    float lb1 = asb.y + adb.y; lb1 = fmaxf(lb1, 0.2f * lb1);
    int ca = ((sa >= SRC_SPLIT) ? 4 : 0) + (ea & 3);   // src-half keyed chain
    int cb = ((sb >= SRC_SPLIT) ? 4 : 0) + (eb & 3);
    int olda = atomicExch(&head8[da * 8 + ca], ea);
    int oldb = atomicExch(&head8[db * 8 + cb], eb);
    edge4[ea] = make_int4(sa, olda, __float_as_int(__expf(la0)), __float_as_int(__expf(la1)));
    edge4[eb] = make_int4(sb, oldb, __float_as_int(__expf(lb0)), __float_as_int(__expf(lb1)));
    return;
  }
  __shared__ unsigned short Wt[64 * 136];   // [n][k] bf16 (W^T), padded, 17.4 KB
  __shared__ unsigned short xs[32 * 136];   // [r][k] bf16 (ELU applied), 8.7 KB
  int row0 = bid * 32;
#pragma unroll
  for (int it = 0; it < 4; ++it) {          // stage W^T: 16B vector copy from wt16
    int idx = it * 2048 + tid * 8;          // idx = n*128 + k, k 8-aligned
    int n = idx >> 7, k = idx & 127;
    *(short8*)&Wt[n * 136 + k] = *(const short8*)&wt16[idx];
  }
  for (int i = tid; i < 2048; i += 256) {          // stage x rows (ELU, bf16, packed)
    int r = i >> 6, k2 = (i & 63) * 2;
    int row = row0 + r;
    float v0 = 0.f, v1 = 0.f;
    if (row < NN) { float2 xv = *(const float2*)&x[row * 128 + k2]; v0 = xv.x; v1 = xv.y; }
    v0 = v0 > 0.f ? v0 : __expf(v0) - 1.f;
    v1 = v1 > 0.f ? v1 : __expf(v1) - 1.f;
    *(unsigned*)&xs[r * 136 + k2] = (unsigned)f2bf(v0) | ((unsigned)f2bf(v1) << 16);
  }
  __syncthreads();
  int w = tid >> 6, lane = tid & 63;
  int t = w >> 1, ch = w & 1;               // row-tile, column-half
  int m = lane & 15, quad = lane >> 4;
  float4v acc[2] = {{0, 0, 0, 0}, {0, 0, 0, 0}};
#pragma unroll
  for (int ks = 0; ks < 4; ++ks) {
    int koff = quad * 8 + ks * 32;
    short8 af = *(const short8*)&xs[(t * 16 + m) * 136 + koff];
#pragma unroll
    for (int j = 0; j < 2; ++j) {
      int nt = ch * 2 + j;
      short8 bf = *(const short8*)&Wt[(nt * 16 + m) * 136 + koff];
      acc[j] = __builtin_amdgcn_mfma_f32_16x16x32_bf16(af, bf, acc[j], 0, 0, 0);
    }
  }
#pragma unroll
  for (int j = 0; j < 2; ++j) {
    int nt = ch * 2 + j;
#pragma unroll
    for (int reg = 0; reg < 4; ++reg) {
      float v = acc[j][reg];
      float vhi = __shfl_xor(v, 1);          // partner column (m^1)
      int row = row0 + t * 16 + quad * 4 + reg;
      if (!(m & 1) && row < NN) {
        h2u[row * 32 + nt * 8 + (m >> 1)] =
            (unsigned)f2bf(v) | ((unsigned)f2bf(vhi) << 16);
      }
    }
  }
}

// ---------------- K2: weighted aggregate — src-phased chain walk (VERBATIM R7) -------
__global__ __launch_bounds__(256) void k_agg(
    const unsigned* __restrict__ h2u, const float2* __restrict__ a_src2,
    const float2* __restrict__ a_dst2, const int4* __restrict__ head8v,
    const int4* __restrict__ edge4, const float* __restrict__ bias,
    float* __restrict__ out) {
  int lane = threadIdx.x & 63;
  int half = lane >> 5;
  int n = blockIdx.x * 8 + (threadIdx.x >> 6) * 2 + half;   // node per half-wave
  int c2 = lane & 31;          // column pair: cols 2*c2, 2*c2+1
  int hh = c2 >> 4;            // head of this lane's columns

  float denom, acc0, acc1;
  {   // self loop (PyG add_self_loops), counted once
    float2 as = a_src2[n], ad = a_dst2[n];
    float l0 = (hh ? as.y + ad.y : as.x + ad.x);
    l0 = fmaxf(l0, 0.2f * l0);
    float es = __expf(l0);
    unsigned hv = h2u[n * 32 + c2];
    denom = es; acc0 = es * bflo(hv); acc1 = es * bfhi(hv);
  }

  int4 hdA = head8v[n * 2];        // chains 0..3: src < SRC_SPLIT
  int4 hdB = head8v[n * 2 + 1];    // chains 4..7: src >= SRC_SPLIT
#pragma unroll
  for (int ph = 0; ph < 2; ++ph) {
    int4 hd = ph ? hdB : hdA;
    int e0 = hd.x, e1 = hd.y, e2 = hd.z, e3 = hd.w;
    while (max(max(e0, e1), max(e2, e3)) >= 0) {   // half-uniform
      int4 p0 = edge4[max(e0, 0)];
      int4 p1 = edge4[max(e1, 0)];
      int4 p2 = edge4[max(e2, 0)];
      int4 p3 = edge4[max(e3, 0)];
      unsigned h0 = h2u[p0.x * 32 + c2], h1 = h2u[p1.x * 32 + c2];
      unsigned h2 = h2u[p2.x * 32 + c2], h3 = h2u[p3.x * 32 + c2];
      float x0 = (e0 >= 0) ? __int_as_float(hh ? p0.w : p0.z) : 0.f;
      float x1 = (e1 >= 0) ? __int_as_float(hh ? p1.w : p1.z) : 0.f;
      float x2 = (e2 >= 0) ? __int_as_float(hh ? p2.w : p2.z) : 0.f;
      float x3 = (e3 >= 0) ? __int_as_float(hh ? p3.w : p3.z) : 0.f;
      denom += (x0 + x1) + (x2 + x3);
      acc0 += x0 * bflo(h0) + x1 * bflo(h1) + x2 * bflo(h2) + x3 * bflo(h3);
      acc1 += x0 * bfhi(h0) + x1 * bfhi(h1) + x2 * bfhi(h2) + x3 * bfhi(h3);
      e0 = (e0 >= 0) ? p0.y : -1;
      e1 = (e1 >= 0) ? p1.y : -1;
      e2 = (e2 >= 0) ? p2.y : -1;
      e3 = (e3 >= 0) ? p3.y : -1;
    }
  }
  float inv = 1.f / (denom + 1e-16f);
  float2 b = ((const float2*)bias)[c2];
  ((float2*)out)[n * 32 + c2] = make_float2(acc0 * inv + b.x, acc1 * inv + b.y);
}

extern "C" void kernel_launch(void* const* d_in, const int* in_sizes, int n_in,
                              void* d_out, int out_size, void* d_ws, size_t ws_size,
                              hipStream_t stream) {
  const float* x       = (const float*)d_in[0];
  const float* W       = (const float*)d_in[1];
  const float* att_src = (const float*)d_in[2];
  const float* att_dst = (const float*)d_in[3];
  const float* bias    = (const float*)d_in[4];
  const int* edge_index = (const int*)d_in[5];
  const int* esrc = edge_index;        // edge_index[0, :]
  const int* edst = edge_index + EE;   // edge_index[1, :]

  // Workspace layout:
  char* base = (char*)d_ws;
  unsigned* h2u  = (unsigned*)base;                      // [0     .. 6.4M)   h bf16x2
  float2* a_src2 = (float2*)(base + 6400000);            // [6.4M  .. 6.8M)  50K float2
  float2* a_dst2 = (float2*)(base + 6800000);            // [6.8M  .. 7.2M)  50K float2
  int*    head8  = (int*)(base + 7200000);               // [7.2M  .. 8.8M)  400K i32
  int4*   edge4  = (int4*)(base + 8800000);              // [8.8M  .. 34.4M) 1.6M int4
  // bf16 W^T scratch lives in the OUTPUT buffer (12.8 MB, only written by k_agg,
  // stream-ordered after k_mid's reads) -- avoids growing the workspace.
  unsigned short* wt16 = (unsigned short*)d_out;         // [0 .. 16K) of d_out

  const int PRE_BLOCKS = 1024;
  k_pre<<<PRE_BLOCKS, 256, 0, stream>>>(x, W, att_src, att_dst, a_src2, a_dst2,
                                        head8, wt16, PRE_BLOCKS);
  k_mid<<<PROJ_BLOCKS + EE / 512, 256, 0, stream>>>(x, wt16, esrc, edst, a_src2,
                                                    a_dst2, head8, edge4, h2u);
  k_agg<<<NN / 8, 256, 0, stream>>>(h2u, a_src2, a_dst2, (const int4*)head8,
                                    edge4, bias, (float*)d_out);
}